// Round 6
// baseline (233.869 us; speedup 1.0000x reference)
//
#include <hip/hip_runtime.h>
#include <math.h>

#define BB 4
#define HH 8
#define LL 2048
#define DD 64
#define SK 40            // sample_k == u == 40 for L=2048, FACTOR=5
#define BH (BB*HH)       // 32
#define NC 16            // key-chunks per (bh,u) in attn
#define CK 128           // keys per chunk (NC*CK == LL)

#define S1_NQ 128        // queries per stage1 M-block
#define S1_R  128        // K rows staged per pass
#define S1_P  16         // passes (S1_R * S1_P == LL)
#define S1_STRIDE 68     // padded row stride in floats (272 B, 16B-aligned rows)

__device__ __forceinline__ unsigned ordu(float v) {
    unsigned u = __float_as_uint(v);
    return (u & 0x80000000u) ? ~u : (u | 0x80000000u);
}

__device__ __forceinline__ float dot4(float4 a, float4 b) {
    return a.x * b.x + a.y * b.y + a.z * b.z + a.w * b.w;
}

// ---------------------------------------------------------------------------
// Stage 1: blocks [0,512): compute_M via K-range passes (coalesced K staging
// into LDS, bucketed sample lists). blocks [512,1024): V chunk sums.
__global__ __launch_bounds__(256) void stage1_kernel(
        const float* __restrict__ Q, const float* __restrict__ K,
        const float* __restrict__ V, const int* __restrict__ IDX,
        float* __restrict__ M, float* __restrict__ csum) {
    int tid = threadIdx.x;
    if (blockIdx.x < 512) {
        // ----- compute_M: (bh, chunk of 128 queries) per block.
        int x = blockIdx.x;
        int bhLo = x & 7;                 // XCD affinity
        int r = x >> 3;                   // [0,64)
        int bhHi = r & 3;
        int qc = r >> 2;                  // [0,16)
        int bh = bhHi * 8 + bhLo;
        int qbase = qc * S1_NQ;

        __shared__ float kld[S1_R * S1_STRIDE];   // 34816 B staged K rows
        __shared__ int   sidx[S1_NQ * SK];        // 20480 B bucket-sorted samples
        __shared__ int   soff[S1_NQ * (S1_P + 1)];// 8704 B bucket offsets (absolute)

        // --- per-query counting sort into S1_P range buckets (thread q < 128)
        if (tid < S1_NQ) {
            int vv[SK];
            #pragma unroll
            for (int s = 0; s < SK; ++s)
                vv[s] = IDX[(size_t)(qbase + tid) * SK + s];
            int wp = tid * SK;
            for (int p = 0; p < S1_P; ++p) {
                soff[tid * (S1_P + 1) + p] = wp;
                #pragma unroll
                for (int s = 0; s < SK; ++s) {
                    if ((vv[s] >> 7) == p) sidx[wp++] = vv[s];
                }
            }
            soff[tid * (S1_P + 1) + S1_P] = wp;   // == tid*SK + SK
        }

        // --- Q fragments: 8 lanes/query-group; each group owns 4 queries.
        // Lane c8 holds Q float4 indices {c8, c8+8} = floats [4c8,4c8+4) U [32+4c8,32+4c8+4)
        int G = tid >> 3, c8 = tid & 7;   // G in [0,32)
        const float4* Q4 = (const float4*)Q;
        const float4* K4 = (const float4*)K;
        float4 qr[4][2];
        #pragma unroll
        for (int qi2 = 0; qi2 < 4; ++qi2) {
            int qpos = qbase + G + qi2 * 32;
            qr[qi2][0] = Q4[((size_t)bh * LL + qpos) * 16 + c8];
            qr[qi2][1] = Q4[((size_t)bh * LL + qpos) * 16 + c8 + 8];
        }

        float mx[4] = {-INFINITY, -INFINITY, -INFINITY, -INFINITY};
        float sm[4] = {0.f, 0.f, 0.f, 0.f};

        size_t kb4 = (size_t)bh * LL * 16;
        for (int p = 0; p < S1_P; ++p) {
            __syncthreads();              // covers sort (p=0) and prev-pass readers
            // stage K rows [p*128, p*128+128): fully coalesced, 8 float4/thread
            #pragma unroll
            for (int i = 0; i < 8; ++i) {
                int f = tid + i * 256;    // float4 index within the 128-row window
                int row = f >> 4, j = f & 15;
                float4 v = K4[kb4 + (size_t)(p * S1_R) * 16 + f];
                *(float4*)&kld[row * S1_STRIDE + j * 4] = v;
            }
            __syncthreads();
            // consume this range's buckets.
            // K fragment MUST match Q fragment layout: floats [4c8,4c8+4) and
            // [32+4c8, 32+4c8+4) of the row.  (Round-5 bug: read 8c8..8c8+8.)
            #pragma unroll
            for (int qi2 = 0; qi2 < 4; ++qi2) {
                int q = G + qi2 * 32;
                int b0 = soff[q * (S1_P + 1) + p];
                int b1 = soff[q * (S1_P + 1) + p + 1];
                for (int s = b0; s < b1; ++s) {
                    int kl = sidx[s] - (p << 7);      // [0,128)
                    const float* krow = &kld[kl * S1_STRIDE + c8 * 4];
                    float4 a0 = *(const float4*)krow;
                    float4 a1 = *(const float4*)(krow + 32);
                    float pd = dot4(qr[qi2][0], a0) + dot4(qr[qi2][1], a1);
                    pd += __shfl_xor(pd, 1, 64);
                    pd += __shfl_xor(pd, 2, 64);
                    pd += __shfl_xor(pd, 4, 64);
                    mx[qi2] = fmaxf(mx[qi2], pd);
                    sm[qi2] += pd;
                }
            }
        }
        if (c8 == 0) {
            #pragma unroll
            for (int qi2 = 0; qi2 < 4; ++qi2) {
                int qpos = qbase + G + qi2 * 32;
                M[(size_t)bh * LL + qpos] = mx[qi2] - sm[qi2] * (1.0f / (float)LL);
            }
        }
    } else {
        // ----- vsum: per-(bh,chunk-of-128) column sums of V
        int x = blockIdx.x - 512;         // [0,512)
        int bhLo = x & 7, r = x >> 3;
        int bhHi = r & 3, c = r >> 2;     // c in [0,16)
        int bh = bhHi * 8 + bhLo;
        int d = tid & 63, sg = tid >> 6;
        size_t base = (size_t)bh * LL * DD;
        int row0 = c * 128 + sg * 32;
        float s = 0.f;
        for (int j = 0; j < 32; ++j) s += V[base + (size_t)(row0 + j) * DD + d];
        __shared__ float part[4][DD];
        part[sg][d] = s;
        __syncthreads();
        if (sg == 0)
            csum[((size_t)bh * 16 + c) * DD + d] = part[0][d] + part[1][d] + part[2][d] + part[3][d];
    }
}

// ---------------------------------------------------------------------------
// Stage 2: blocks [0,512) cumsum V -> out; blocks [512,544) radix top-40 of M.
__global__ __launch_bounds__(256) void stage2_kernel(
        const float* __restrict__ V, const float* __restrict__ csum,
        const float* __restrict__ M, float* __restrict__ out,
        int* __restrict__ topk) {
    int tid = threadIdx.x;
    if (blockIdx.x < 512) {
        // ----- cumsum
        int x = blockIdx.x;
        int bhLo = x & 7, r = x >> 3;
        int bhHi = r & 3, c = r >> 2;
        int bh = bhHi * 8 + bhLo;
        int d = tid & 63, sg = tid >> 6;
        size_t base = (size_t)bh * LL * DD;
        int row0 = c * 128 + sg * 32;
        float v[32];
        #pragma unroll
        for (int j = 0; j < 32; ++j) v[j] = V[base + (size_t)(row0 + j) * DD + d];
        float s = 0.f;
        #pragma unroll
        for (int j = 0; j < 32; ++j) s += v[j];
        __shared__ float part[4][DD];
        part[sg][d] = s;
        __syncthreads();
        float pre = 0.f;
        for (int cc = 0; cc < c; ++cc) pre += csum[((size_t)bh * 16 + cc) * DD + d];
        for (int ss = 0; ss < sg; ++ss) pre += part[ss][d];
        float acc = pre;
        #pragma unroll
        for (int j = 0; j < 32; ++j) {
            acc += v[j];
            out[base + (size_t)(row0 + j) * DD + d] = acc;
        }
    } else {
        // ----- radix top-40 (8 bits/pass, 4 passes); unordered emission.
        int bh = blockIdx.x - 512;
        __shared__ unsigned hist[256];
        __shared__ unsigned bc_prefix, bc_need;
        __shared__ unsigned cnt_gt, cnt_eq;
        __shared__ int eqlist[128];

        unsigned v[8];
        #pragma unroll
        for (int j = 0; j < 8; ++j)
            v[j] = ordu(M[(size_t)bh * LL + tid + j * 256]);

        unsigned prefix = 0, need = SK;
        #pragma unroll
        for (int pass = 0; pass < 4; ++pass) {
            const int s = 24 - 8 * pass;
            const unsigned maskHigh = (pass == 0) ? 0u : (0xFFFFFFFFu << (s + 8));
            hist[tid] = 0;
            __syncthreads();
            #pragma unroll
            for (int j = 0; j < 8; ++j)
                if (((v[j] ^ prefix) & maskHigh) == 0)
                    atomicAdd(&hist[(v[j] >> s) & 0xFF], 1u);
            __syncthreads();
            unsigned above = 0;
            for (int b = tid + 1; b < 256; ++b) above += hist[b];
            if (above < need && above + hist[tid] >= need) {
                bc_prefix = prefix | ((unsigned)tid << s);
                bc_need = need - above;
            }
            __syncthreads();
            prefix = bc_prefix;
            need = bc_need;
            __syncthreads();
        }
        unsigned T = prefix;
        if (tid == 0) { cnt_gt = 0; cnt_eq = 0; }
        __syncthreads();
        #pragma unroll
        for (int j = 0; j < 8; ++j) {
            int idx = tid + j * 256;
            if (v[j] > T) { unsigned p = atomicAdd(&cnt_gt, 1u); topk[bh * SK + p] = idx; }
            else if (v[j] == T) { unsigned p = atomicAdd(&cnt_eq, 1u); if (p < 128) eqlist[p] = idx; }
        }
        __syncthreads();
        if (tid == 0) {
            int ne = (int)min(cnt_eq, 128u);
            unsigned base = cnt_gt;       // == SK - need
            for (unsigned r2 = 0; r2 < need; ++r2) {
                int bj = 0, bv = 0x7FFFFFFF;
                for (int j = 0; j < ne; ++j)
                    if (eqlist[j] < bv) { bv = eqlist[j]; bj = j; }
                topk[bh * SK + base + r2] = bv;
                eqlist[bj] = 0x7FFFFFFF;
            }
        }
    }
}

// ---------------------------------------------------------------------------
// Stage 3: one block per (bh, key-chunk of CK). Stages all 40 Q rows in LDS,
// computes scores for all 40 u's vs the chunk (K/V read ONCE per bh), writes
// per-(u,chunk) partials (m, sumexp, weighted-V). Fully-masked chunks emit
// pm=-inf/pl=0/po=0. Combine kernel merges.
__global__ __launch_bounds__(256) void attn_kernel(
        const float* __restrict__ Q, const float* __restrict__ K,
        const float* __restrict__ V, const int* __restrict__ topk,
        float* __restrict__ pm, float* __restrict__ pl,
        float* __restrict__ po) {
    int x = blockIdx.x;               // [0, 512)
    int bhLo = x & 7;                 // XCD affinity: 4 bh per XCD -> 4MB K/V in L2
    int r = x >> 3;                   // [0,64)
    int c = r & 15;                   // chunk [0,NC)
    int bhHi = r >> 4;                // [0,4)
    int bh = bhHi * 8 + bhLo;
    int tid = threadIdx.x;
    int w = tid >> 6, lane = tid & 63;
    int cbase = c * CK;

    __shared__ int qp[SK];
    __shared__ float4 sq4[SK][16];     // 10 KB: 40 Q rows
    __shared__ float SC[CK][SK + 1];   // 21 KB, pad 41 -> conflict-free

    if (tid < SK) qp[tid] = topk[bh * SK + tid];
    __syncthreads();
    const float4* Q4 = (const float4*)Q;
    const float4* K4 = (const float4*)K;
    const float4* V4 = (const float4*)V;
    for (int i = tid; i < SK * 16; i += 256) {
        int u = i >> 4, j = i & 15;
        sq4[u][j] = Q4[((size_t)bh * LL + qp[u]) * 16 + j];
    }
    __syncthreads();

    // ---- Phase A: scores. thread = (key kk, half of D); K half-row in regs.
    {
        int half = tid & 1;
        int kk = tid >> 1;            // [0,128)
        int kg = cbase + kk;          // global key index
        size_t kb4 = (size_t)bh * LL * 16;
        float4 kreg[8];
        const float4* kr = K4 + kb4 + (size_t)kg * 16 + half * 8;
        #pragma unroll
        for (int j = 0; j < 8; ++j) kreg[j] = kr[j];
        #pragma unroll 4
        for (int u = 0; u < SK; ++u) {
            int qpu = qp[u];
            if (cbase > qpu) {        // chunk fully masked for this u (uniform)
                if (half == 0) SC[kk][u] = -INFINITY;
                continue;
            }
            float pa = 0.f, pb = 0.f;
            #pragma unroll
            for (int j = 0; j < 4; ++j) {
                float4 qv = sq4[u][half * 8 + j];
                pa += kreg[j].x * qv.x + kreg[j].y * qv.y + kreg[j].z * qv.z + kreg[j].w * qv.w;
            }
            #pragma unroll
            for (int j = 4; j < 8; ++j) {
                float4 qv = sq4[u][half * 8 + j];
                pb += kreg[j].x * qv.x + kreg[j].y * qv.y + kreg[j].z * qv.z + kreg[j].w * qv.w;
            }
            float p = pa + pb;
            p += __shfl_xor(p, 1, 64);   // combine the two halves
            if (half == 0) SC[kk][u] = (kg <= qpu) ? p * 0.125f : -INFINITY;
        }
    }
    __syncthreads();

    // ---- Phase B: per-u chunk max + exp + sumexp (wave w handles u = w,w+4,...)
    for (int u = w; u < SK; u += 4) {
        float s0 = SC[lane][u], s1 = SC[lane + 64][u];
        float m = fmaxf(s0, s1);
        #pragma unroll
        for (int off = 32; off > 0; off >>= 1) m = fmaxf(m, __shfl_xor(m, off, 64));
        float e0 = 0.f, e1 = 0.f;
        if (m != -INFINITY) {
            e0 = expf(s0 - m);           // s==-inf -> 0
            e1 = expf(s1 - m);
        }
        SC[lane][u] = e0;
        SC[lane + 64][u] = e1;
        float ls = e0 + e1;
        #pragma unroll
        for (int off = 32; off > 0; off >>= 1) ls += __shfl_xor(ls, off, 64);
        if (lane == 0) {
            size_t pb = (size_t)(bh * SK + u) * NC + c;
            pm[pb] = m;
            pl[pb] = ls;
        }
    }
    __syncthreads();

    // ---- Phase C: PV = P(40xCK) x V(CKx64). thread = (ks, dg, ug):
    // 10 u x 4 d tile per thread, k-split 4 ways, shfl-combine.
    {
        int ks = tid & 3;
        int dg = (tid >> 2) & 15;
        int ug = tid >> 6;            // == w
        int u0 = ug * 10;
        float4 acc[10];
        #pragma unroll
        for (int i = 0; i < 10; ++i) acc[i] = make_float4(0.f, 0.f, 0.f, 0.f);
        for (int t = 0; t < CK / 4; ++t) {
            int k = t * 4 + ks;
            float4 vv = V4[((size_t)bh * LL + cbase + k) * 16 + dg];
            #pragma unroll
            for (int i = 0; i < 10; ++i) {
                float pw = SC[k][u0 + i];
                acc[i].x += pw * vv.x; acc[i].y += pw * vv.y;
                acc[i].z += pw * vv.z; acc[i].w += pw * vv.w;
            }
        }
        #pragma unroll
        for (int i = 0; i < 10; ++i) {
            acc[i].x += __shfl_xor(acc[i].x, 1, 64); acc[i].x += __shfl_xor(acc[i].x, 2, 64);
            acc[i].y += __shfl_xor(acc[i].y, 1, 64); acc[i].y += __shfl_xor(acc[i].y, 2, 64);
            acc[i].z += __shfl_xor(acc[i].z, 1, 64); acc[i].z += __shfl_xor(acc[i].z, 2, 64);
            acc[i].w += __shfl_xor(acc[i].w, 1, 64); acc[i].w += __shfl_xor(acc[i].w, 2, 64);
        }
        if (ks == 0) {
            #pragma unroll
            for (int i = 0; i < 10; ++i) {
                float4* dst = (float4*)&po[((size_t)(bh * SK + u0 + i) * NC + c) * DD + dg * 4];
                *dst = acc[i];
            }
        }
    }
}

// ---------------------------------------------------------------------------
// Stage 4: combine partials. One wave per (bh,u) group; 4 groups per block.
__global__ __launch_bounds__(256) void combine_kernel(
        const float* __restrict__ pm, const float* __restrict__ pl,
        const float* __restrict__ po, const int* __restrict__ topk,
        float* __restrict__ out) {
    int g = blockIdx.x * 4 + (threadIdx.x >> 6);   // [0, 1280)
    int d = threadIdx.x & 63;
    int qpos = topk[g];
    int bh = g / SK;
    size_t gb = (size_t)g * NC;
    float gm = -INFINITY;
    #pragma unroll
    for (int j = 0; j < NC; ++j) gm = fmaxf(gm, pm[gb + j]);
    float L = 0.f, o = 0.f;
    #pragma unroll
    for (int j = 0; j < NC; ++j) {
        float pmj = pm[gb + j];
        float wj = (pmj == -INFINITY) ? 0.f : expf(pmj - gm);
        L += pl[gb + j] * wj;
        o += po[(gb + j) * DD + d] * wj;
    }
    out[((size_t)bh * LL + qpos) * DD + d] = o / L;
}

// ---------------------------------------------------------------------------
extern "C" void kernel_launch(void* const* d_in, const int* in_sizes, int n_in,
                              void* d_out, int out_size, void* d_ws, size_t ws_size,
                              hipStream_t stream) {
    const float* Q   = (const float*)d_in[0];
    const float* K   = (const float*)d_in[1];
    const float* V   = (const float*)d_in[2];
    const int*   IDX = (const int*)d_in[3];
    float* out = (float*)d_out;

    char* ws = (char*)d_ws;
    float* M    = (float*)ws;  ws += (size_t)BH * LL * sizeof(float);                 // 256 KB
    int*   topk = (int*)ws;    ws += ((size_t)BH * SK * sizeof(int) + 255) & ~255ull;
    float* csum = (float*)ws;  ws += (size_t)BH * 16 * DD * sizeof(float);            // 128 KB
    float* pm   = (float*)ws;  ws += ((size_t)BH * SK * NC * sizeof(float) + 255) & ~255ull;
    float* pl   = (float*)ws;  ws += ((size_t)BH * SK * NC * sizeof(float) + 255) & ~255ull;
    float* po   = (float*)ws;  // BH*SK*NC*DD floats = 5.24 MB

    stage1_kernel<<<1024, 256, 0, stream>>>(Q, K, V, IDX, M, csum);
    stage2_kernel<<<544, 256, 0, stream>>>(V, csum, M, out, topk);
    attn_kernel<<<BH * NC, 256, 0, stream>>>(Q, K, V, topk, pm, pl, po);
    combine_kernel<<<BH * SK / 4, 256, 0, stream>>>(pm, pl, po, topk, out);
}

// Round 7
// 216.197 us; speedup vs baseline: 1.0817x; 1.0817x over previous
//
#include <hip/hip_runtime.h>
#include <math.h>

#define BB 4
#define HH 8
#define LL 2048
#define DD 64
#define SK 40            // sample_k == u == 40 for L=2048, FACTOR=5
#define BH (BB*HH)       // 32
#define NC 16            // key-chunks per (bh,u) in attn
#define CK 128           // keys per chunk (NC*CK == LL)

#define S1_NQ 128        // queries per stage1 M-block
#define S1_R  128        // K rows staged per pass
#define S1_P  16         // passes (S1_R * S1_P == LL)
#define S1_STR 68        // padded row stride in floats (272 B, 16B-aligned rows)
// dynamic LDS bytes: (8704+8704+5248)*4 + (5120+2176+17+16)*4 = 119940
#define S1_SMEM 119944

__device__ __forceinline__ unsigned ordu(float v) {
    unsigned u = __float_as_uint(v);
    return (u & 0x80000000u) ? ~u : (u | 0x80000000u);
}

__device__ __forceinline__ float dot4(float4 a, float4 b) {
    return a.x * b.x + a.y * b.y + a.z * b.z + a.w * b.w;
}

// ---------------------------------------------------------------------------
// Stage 1 (512 threads/block): blocks [0,512): compute_M via K-range passes
// with a block-global pass-sorted worklist (balanced 8-lane-group consumption).
// blocks [512,1024): V chunk sums.
__global__ __launch_bounds__(512) void stage1_kernel(
        const float* __restrict__ Q, const float* __restrict__ K,
        const float* __restrict__ V, const int* __restrict__ IDX,
        float* __restrict__ M, float* __restrict__ csum) {
    extern __shared__ char smem[];
    int tid = threadIdx.x;
    if (blockIdx.x < 512) {
        // ----- compute_M: (bh, chunk of 128 queries) per block.
        int x = blockIdx.x;
        int bhLo = x & 7;                 // XCD affinity
        int r = x >> 3;                   // [0,64)
        int bhHi = r & 3;
        int qc = r >> 2;                  // [0,16)
        int bh = bhHi * 8 + bhLo;
        int qbase = qc * S1_NQ;

        float* kK   = (float*)smem;                    // 128*68 floats (34816 B)
        float* kQ   = kK + S1_R * S1_STR;              // 128*68 floats (34816 B)
        float* SCb  = kQ + S1_NQ * S1_STR;             // 128*41 floats (20992 B)
        int*   list = (int*)(SCb + S1_NQ * 41);        // 5120 ints    (20480 B)
        int*   cpos = list + S1_NQ * SK;               // 128*17 ints  ( 8704 B)
        int*   pbase= cpos + S1_NQ * 17;               // 17 ints
        int*   ptot = pbase + 17;                      // 16 ints

        const float4* Q4 = (const float4*)Q;
        const float4* K4 = (const float4*)K;
        size_t kb4 = (size_t)bh * LL * 16;

        // stage Q tile (128 rows), coalesced: 2048 float4s, 4 per thread
        #pragma unroll
        for (int i = 0; i < 4; ++i) {
            int f = tid + i * 512;
            int row = f >> 4, j = f & 15;
            float4 v = Q4[((size_t)bh * LL + qbase) * 16 + f];
            *(float4*)&kQ[row * S1_STR + j * 4] = v;
        }
        for (int i = tid; i < S1_NQ * 17; i += 512) cpos[i] = 0;
        __syncthreads();

        // ---- counting sort of the 5120 (q,s) items by pass = ks>>7
        int vv[SK];
        if (tid < S1_NQ) {
            #pragma unroll
            for (int s = 0; s < SK; ++s) {
                vv[s] = IDX[(size_t)(qbase + tid) * SK + s];
                cpos[tid * 17 + (vv[s] >> 7)]++;
            }
        }
        __syncthreads();
        if (tid < S1_P) {                 // exclusive prefix over q, per pass
            int run = 0;
            for (int q = 0; q < S1_NQ; ++q) {
                int t = cpos[q * 17 + tid];
                cpos[q * 17 + tid] = run;
                run += t;
            }
            ptot[tid] = run;
        }
        __syncthreads();
        if (tid == 0) {
            int run = 0;
            for (int p = 0; p < S1_P; ++p) { pbase[p] = run; run += ptot[p]; }
            pbase[S1_P] = run;            // == 5120
        }
        __syncthreads();
        if (tid < S1_NQ) {
            #pragma unroll
            for (int s = 0; s < SK; ++s) {
                int p = vv[s] >> 7;
                int dest = pbase[p] + cpos[tid * 17 + p]++;
                list[dest] = (tid << 16) | (s << 8) | (vv[s] & 127);
            }
        }

        // ---- main loop: 16 passes of {stage 128 K rows, consume worklist}
        int g = tid >> 3, c8 = tid & 7;   // 64 groups of 8 lanes
        for (int p = 0; p < S1_P; ++p) {
            __syncthreads();              // protects list (p=0) / prev consume
            #pragma unroll
            for (int i = 0; i < 4; ++i) {
                int f = tid + i * 512;
                int row = f >> 4, j = f & 15;
                float4 v = K4[kb4 + (size_t)(p * S1_R) * 16 + f];
                *(float4*)&kK[row * S1_STR + j * 4] = v;
            }
            __syncthreads();
            int pb = pbase[p], pe = pbase[p + 1];
            for (int i = pb + g; i < pe; i += 64) {
                int it = list[i];
                int q = it >> 16, slot = (it >> 8) & 0xFF, kl = it & 0xFF;
                const float* kr = &kK[kl * S1_STR + c8 * 4];
                const float* qr = &kQ[q * S1_STR + c8 * 4];
                float4 a0 = *(const float4*)kr;
                float4 a1 = *(const float4*)(kr + 32);
                float4 b0 = *(const float4*)qr;
                float4 b1 = *(const float4*)(qr + 32);
                float pd = dot4(a0, b0) + dot4(a1, b1);
                pd += __shfl_xor(pd, 1, 64);
                pd += __shfl_xor(pd, 2, 64);
                pd += __shfl_xor(pd, 4, 64);
                if (c8 == 0) SCb[q * 41 + slot] = pd;
            }
        }
        __syncthreads();

        // ---- final per-query reduce over the 40 score slots
        if (tid < S1_NQ) {
            float mx = -INFINITY, sm = 0.f;
            #pragma unroll
            for (int s = 0; s < SK; ++s) {
                float v = SCb[tid * 41 + s];
                mx = fmaxf(mx, v);
                sm += v;
            }
            M[(size_t)bh * LL + qbase + tid] = mx - sm * (1.0f / (float)LL);
        }
    } else {
        // ----- vsum: per-(bh,chunk-of-128) column sums of V (512 threads)
        int x = blockIdx.x - 512;         // [0,512)
        int bhLo = x & 7, r = x >> 3;
        int bhHi = r & 3, c = r >> 2;     // c in [0,16)
        int bh = bhHi * 8 + bhLo;
        int d = tid & 63, sg = tid >> 6;  // sg in [0,8)
        size_t base = (size_t)bh * LL * DD;
        int row0 = c * 128 + sg * 16;
        float s = 0.f;
        for (int j = 0; j < 16; ++j) s += V[base + (size_t)(row0 + j) * DD + d];
        float* part = (float*)smem;       // 8*64 floats
        part[sg * DD + d] = s;
        __syncthreads();
        if (sg == 0) {
            float t = 0.f;
            #pragma unroll
            for (int k = 0; k < 8; ++k) t += part[k * DD + d];
            csum[((size_t)bh * 16 + c) * DD + d] = t;
        }
    }
}

// ---------------------------------------------------------------------------
// Stage 2: blocks [0,512) cumsum V -> out; blocks [512,544) radix top-40 of M.
__global__ __launch_bounds__(256) void stage2_kernel(
        const float* __restrict__ V, const float* __restrict__ csum,
        const float* __restrict__ M, float* __restrict__ out,
        int* __restrict__ topk) {
    int tid = threadIdx.x;
    if (blockIdx.x < 512) {
        // ----- cumsum
        int x = blockIdx.x;
        int bhLo = x & 7, r = x >> 3;
        int bhHi = r & 3, c = r >> 2;
        int bh = bhHi * 8 + bhLo;
        int d = tid & 63, sg = tid >> 6;
        size_t base = (size_t)bh * LL * DD;
        int row0 = c * 128 + sg * 32;
        float v[32];
        #pragma unroll
        for (int j = 0; j < 32; ++j) v[j] = V[base + (size_t)(row0 + j) * DD + d];
        float s = 0.f;
        #pragma unroll
        for (int j = 0; j < 32; ++j) s += v[j];
        __shared__ float part[4][DD];
        part[sg][d] = s;
        __syncthreads();
        float pre = 0.f;
        for (int cc = 0; cc < c; ++cc) pre += csum[((size_t)bh * 16 + cc) * DD + d];
        for (int ss = 0; ss < sg; ++ss) pre += part[ss][d];
        float acc = pre;
        #pragma unroll
        for (int j = 0; j < 32; ++j) {
            acc += v[j];
            out[base + (size_t)(row0 + j) * DD + d] = acc;
        }
    } else {
        // ----- radix top-40 (8 bits/pass, 4 passes); unordered emission.
        int bh = blockIdx.x - 512;
        __shared__ unsigned hist[256];
        __shared__ unsigned bc_prefix, bc_need;
        __shared__ unsigned cnt_gt, cnt_eq;
        __shared__ int eqlist[128];

        unsigned v[8];
        #pragma unroll
        for (int j = 0; j < 8; ++j)
            v[j] = ordu(M[(size_t)bh * LL + tid + j * 256]);

        unsigned prefix = 0, need = SK;
        #pragma unroll
        for (int pass = 0; pass < 4; ++pass) {
            const int s = 24 - 8 * pass;
            const unsigned maskHigh = (pass == 0) ? 0u : (0xFFFFFFFFu << (s + 8));
            hist[tid] = 0;
            __syncthreads();
            #pragma unroll
            for (int j = 0; j < 8; ++j)
                if (((v[j] ^ prefix) & maskHigh) == 0)
                    atomicAdd(&hist[(v[j] >> s) & 0xFF], 1u);
            __syncthreads();
            unsigned above = 0;
            for (int b = tid + 1; b < 256; ++b) above += hist[b];
            if (above < need && above + hist[tid] >= need) {
                bc_prefix = prefix | ((unsigned)tid << s);
                bc_need = need - above;
            }
            __syncthreads();
            prefix = bc_prefix;
            need = bc_need;
            __syncthreads();
        }
        unsigned T = prefix;
        if (tid == 0) { cnt_gt = 0; cnt_eq = 0; }
        __syncthreads();
        #pragma unroll
        for (int j = 0; j < 8; ++j) {
            int idx = tid + j * 256;
            if (v[j] > T) { unsigned p = atomicAdd(&cnt_gt, 1u); topk[bh * SK + p] = idx; }
            else if (v[j] == T) { unsigned p = atomicAdd(&cnt_eq, 1u); if (p < 128) eqlist[p] = idx; }
        }
        __syncthreads();
        if (tid == 0) {
            int ne = (int)min(cnt_eq, 128u);
            unsigned base = cnt_gt;       // == SK - need
            for (unsigned r2 = 0; r2 < need; ++r2) {
                int bj = 0, bv = 0x7FFFFFFF;
                for (int j = 0; j < ne; ++j)
                    if (eqlist[j] < bv) { bv = eqlist[j]; bj = j; }
                topk[bh * SK + base + r2] = bv;
                eqlist[bj] = 0x7FFFFFFF;
            }
        }
    }
}

// ---------------------------------------------------------------------------
// Stage 3: one block per (bh, key-chunk of CK). Stages all 40 Q rows in LDS,
// computes scores for all 40 u's vs the chunk (K/V read ONCE per bh), writes
// per-(u,chunk) partials (m, sumexp, weighted-V). Fully-masked chunks emit
// pm=-inf/pl=0/po=0. Combine kernel merges.
__global__ __launch_bounds__(256) void attn_kernel(
        const float* __restrict__ Q, const float* __restrict__ K,
        const float* __restrict__ V, const int* __restrict__ topk,
        float* __restrict__ pm, float* __restrict__ pl,
        float* __restrict__ po) {
    int x = blockIdx.x;               // [0, 512)
    int bhLo = x & 7;                 // XCD affinity: 4 bh per XCD -> 4MB K/V in L2
    int r = x >> 3;                   // [0,64)
    int c = r & 15;                   // chunk [0,NC)
    int bhHi = r >> 4;                // [0,4)
    int bh = bhHi * 8 + bhLo;
    int tid = threadIdx.x;
    int w = tid >> 6, lane = tid & 63;
    int cbase = c * CK;

    __shared__ int qp[SK];
    __shared__ float4 sq4[SK][16];     // 10 KB: 40 Q rows
    __shared__ float SC[CK][SK + 1];   // 21 KB, pad 41 -> conflict-free

    if (tid < SK) qp[tid] = topk[bh * SK + tid];
    __syncthreads();
    const float4* Q4 = (const float4*)Q;
    const float4* K4 = (const float4*)K;
    const float4* V4 = (const float4*)V;
    for (int i = tid; i < SK * 16; i += 256) {
        int u = i >> 4, j = i & 15;
        sq4[u][j] = Q4[((size_t)bh * LL + qp[u]) * 16 + j];
    }
    __syncthreads();

    // ---- Phase A: scores. thread = (key kk, half of D); K half-row in regs.
    {
        int half = tid & 1;
        int kk = tid >> 1;            // [0,128)
        int kg = cbase + kk;          // global key index
        size_t kb4 = (size_t)bh * LL * 16;
        float4 kreg[8];
        const float4* kr = K4 + kb4 + (size_t)kg * 16 + half * 8;
        #pragma unroll
        for (int j = 0; j < 8; ++j) kreg[j] = kr[j];
        #pragma unroll 4
        for (int u = 0; u < SK; ++u) {
            int qpu = qp[u];
            if (cbase > qpu) {        // chunk fully masked for this u (uniform)
                if (half == 0) SC[kk][u] = -INFINITY;
                continue;
            }
            float pa = 0.f, pb = 0.f;
            #pragma unroll
            for (int j = 0; j < 4; ++j) {
                float4 qv = sq4[u][half * 8 + j];
                pa += kreg[j].x * qv.x + kreg[j].y * qv.y + kreg[j].z * qv.z + kreg[j].w * qv.w;
            }
            #pragma unroll
            for (int j = 4; j < 8; ++j) {
                float4 qv = sq4[u][half * 8 + j];
                pb += kreg[j].x * qv.x + kreg[j].y * qv.y + kreg[j].z * qv.z + kreg[j].w * qv.w;
            }
            float p = pa + pb;
            p += __shfl_xor(p, 1, 64);   // combine the two halves
            if (half == 0) SC[kk][u] = (kg <= qpu) ? p * 0.125f : -INFINITY;
        }
    }
    __syncthreads();

    // ---- Phase B: per-u chunk max + exp + sumexp (wave w handles u = w,w+4,...)
    for (int u = w; u < SK; u += 4) {
        float s0 = SC[lane][u], s1 = SC[lane + 64][u];
        float m = fmaxf(s0, s1);
        #pragma unroll
        for (int off = 32; off > 0; off >>= 1) m = fmaxf(m, __shfl_xor(m, off, 64));
        float e0 = 0.f, e1 = 0.f;
        if (m != -INFINITY) {
            e0 = expf(s0 - m);           // s==-inf -> 0
            e1 = expf(s1 - m);
        }
        SC[lane][u] = e0;
        SC[lane + 64][u] = e1;
        float ls = e0 + e1;
        #pragma unroll
        for (int off = 32; off > 0; off >>= 1) ls += __shfl_xor(ls, off, 64);
        if (lane == 0) {
            size_t pb = (size_t)(bh * SK + u) * NC + c;
            pm[pb] = m;
            pl[pb] = ls;
        }
    }
    __syncthreads();

    // ---- Phase C: PV = P(40xCK) x V(CKx64). thread = (ks, dg, ug):
    // 10 u x 4 d tile per thread, k-split 4 ways, shfl-combine.
    {
        int ks = tid & 3;
        int dg = (tid >> 2) & 15;
        int ug = tid >> 6;            // == w
        int u0 = ug * 10;
        float4 acc[10];
        #pragma unroll
        for (int i = 0; i < 10; ++i) acc[i] = make_float4(0.f, 0.f, 0.f, 0.f);
        for (int t = 0; t < CK / 4; ++t) {
            int k = t * 4 + ks;
            float4 vv = V4[((size_t)bh * LL + cbase + k) * 16 + dg];
            #pragma unroll
            for (int i = 0; i < 10; ++i) {
                float pw = SC[k][u0 + i];
                acc[i].x += pw * vv.x; acc[i].y += pw * vv.y;
                acc[i].z += pw * vv.z; acc[i].w += pw * vv.w;
            }
        }
        #pragma unroll
        for (int i = 0; i < 10; ++i) {
            acc[i].x += __shfl_xor(acc[i].x, 1, 64); acc[i].x += __shfl_xor(acc[i].x, 2, 64);
            acc[i].y += __shfl_xor(acc[i].y, 1, 64); acc[i].y += __shfl_xor(acc[i].y, 2, 64);
            acc[i].z += __shfl_xor(acc[i].z, 1, 64); acc[i].z += __shfl_xor(acc[i].z, 2, 64);
            acc[i].w += __shfl_xor(acc[i].w, 1, 64); acc[i].w += __shfl_xor(acc[i].w, 2, 64);
        }
        if (ks == 0) {
            #pragma unroll
            for (int i = 0; i < 10; ++i) {
                float4* dst = (float4*)&po[((size_t)(bh * SK + u0 + i) * NC + c) * DD + dg * 4];
                *dst = acc[i];
            }
        }
    }
}

// ---------------------------------------------------------------------------
// Stage 4: combine partials. One wave per (bh,u) group; 4 groups per block.
__global__ __launch_bounds__(256) void combine_kernel(
        const float* __restrict__ pm, const float* __restrict__ pl,
        const float* __restrict__ po, const int* __restrict__ topk,
        float* __restrict__ out) {
    int g = blockIdx.x * 4 + (threadIdx.x >> 6);   // [0, 1280)
    int d = threadIdx.x & 63;
    int qpos = topk[g];
    int bh = g / SK;
    size_t gb = (size_t)g * NC;
    float gm = -INFINITY;
    #pragma unroll
    for (int j = 0; j < NC; ++j) gm = fmaxf(gm, pm[gb + j]);
    float L = 0.f, o = 0.f;
    #pragma unroll
    for (int j = 0; j < NC; ++j) {
        float pmj = pm[gb + j];
        float wj = (pmj == -INFINITY) ? 0.f : expf(pmj - gm);
        L += pl[gb + j] * wj;
        o += po[(gb + j) * DD + d] * wj;
    }
    out[((size_t)bh * LL + qpos) * DD + d] = o / L;
}

// ---------------------------------------------------------------------------
extern "C" void kernel_launch(void* const* d_in, const int* in_sizes, int n_in,
                              void* d_out, int out_size, void* d_ws, size_t ws_size,
                              hipStream_t stream) {
    const float* Q   = (const float*)d_in[0];
    const float* K   = (const float*)d_in[1];
    const float* V   = (const float*)d_in[2];
    const int*   IDX = (const int*)d_in[3];
    float* out = (float*)d_out;

    static bool inited = false;
    if (!inited) {
        hipFuncSetAttribute((const void*)stage1_kernel,
                            hipFuncAttributeMaxDynamicSharedMemorySize, 131072);
        inited = true;
    }

    char* ws = (char*)d_ws;
    float* M    = (float*)ws;  ws += (size_t)BH * LL * sizeof(float);                 // 256 KB
    int*   topk = (int*)ws;    ws += ((size_t)BH * SK * sizeof(int) + 255) & ~255ull;
    float* csum = (float*)ws;  ws += (size_t)BH * 16 * DD * sizeof(float);            // 128 KB
    float* pm   = (float*)ws;  ws += ((size_t)BH * SK * NC * sizeof(float) + 255) & ~255ull;
    float* pl   = (float*)ws;  ws += ((size_t)BH * SK * NC * sizeof(float) + 255) & ~255ull;
    float* po   = (float*)ws;  // BH*SK*NC*DD floats = 5.24 MB

    stage1_kernel<<<1024, 512, S1_SMEM, stream>>>(Q, K, V, IDX, M, csum);
    stage2_kernel<<<544, 256, 0, stream>>>(V, csum, M, out, topk);
    attn_kernel<<<BH * NC, 256, 0, stream>>>(Q, K, V, topk, pm, pl, po);
    combine_kernel<<<BH * SK / 4, 256, 0, stream>>>(pm, pl, po, topk, out);
}

// Round 8
// 165.044 us; speedup vs baseline: 1.4170x; 1.3099x over previous
//
#include <hip/hip_runtime.h>
#include <math.h>

#define BB 4
#define HH 8
#define LL 2048
#define DD 64
#define SK 40            // sample_k == u == 40 for L=2048, FACTOR=5
#define BH (BB*HH)       // 32
#define NC 16            // key-chunks per (bh,u) in attn
#define CK 128           // keys per chunk (NC*CK == LL)

__device__ __forceinline__ unsigned ordu(float v) {
    unsigned u = __float_as_uint(v);
    return (u & 0x80000000u) ? ~u : (u | 0x80000000u);
}

// ---------------------------------------------------------------------------
// M-compute: round-0 gather (best measured variant: 44 us, VGPR 28).
// 4 lanes/query, 16 queries/wave, 64 queries/block, 1024 blocks.
__global__ __launch_bounds__(256) void mkern(
        const float* __restrict__ Q, const float* __restrict__ K,
        const int* __restrict__ IDX, float* __restrict__ M) {
    int tid = threadIdx.x;
    int x = blockIdx.x;
    int bhLo = x & 7;
    int r = x >> 3;                   // [0,128)
    int bhHi = r & 3;
    int chunk = r >> 2;               // [0,32)
    int bh = bhHi * 8 + bhLo;
    int qbase = chunk * 64;
    int w = tid >> 6, lane = tid & 63;
    int qw = lane >> 2, c = lane & 3;
    int qi = w * 16 + qw;
    int qpos = qbase + qi;

    __shared__ int sidx[64 * SK];     // 10 KB
    for (int i = tid; i < 64 * SK; i += 256) sidx[i] = IDX[(size_t)qbase * SK + i];

    const float4* Q4 = (const float4*)Q;
    const float4* K4 = (const float4*)K;
    float4 qreg[4];
    #pragma unroll
    for (int j = 0; j < 4; ++j)
        qreg[j] = Q4[((size_t)bh * LL + qpos) * 16 + j * 4 + c];
    __syncthreads();

    size_t kb4 = (size_t)bh * LL * 16;
    float mx = -INFINITY, sm = 0.f;
    #pragma unroll 8
    for (int s = 0; s < SK; ++s) {
        int ks = sidx[qi * SK + s];
        const float4* kr = K4 + kb4 + (size_t)ks * 16;
        float p = 0.f;
        #pragma unroll
        for (int j = 0; j < 4; ++j) {
            float4 kv = kr[j * 4 + c];
            p += qreg[j].x * kv.x + qreg[j].y * kv.y + qreg[j].z * kv.z + qreg[j].w * kv.w;
        }
        p += __shfl_xor(p, 1, 64);
        p += __shfl_xor(p, 2, 64);
        mx = fmaxf(mx, p);
        sm += p;
    }
    if (c == 0) M[(size_t)bh * LL + qpos] = mx - sm * (1.0f / (float)LL);
}

// ---------------------------------------------------------------------------
// vsum: per-(bh,chunk-of-128) column sums of V. 512 blocks.
__global__ __launch_bounds__(256) void vsum_kernel(
        const float* __restrict__ V, float* __restrict__ csum) {
    int tid = threadIdx.x;
    int x = blockIdx.x;               // [0,512)
    int bhLo = x & 7, r = x >> 3;
    int bhHi = r & 3, c = r >> 2;     // c in [0,16)
    int bh = bhHi * 8 + bhLo;
    int d = tid & 63, sg = tid >> 6;
    size_t base = (size_t)bh * LL * DD;
    int row0 = c * 128 + sg * 32;
    float s = 0.f;
    for (int j = 0; j < 32; ++j) s += V[base + (size_t)(row0 + j) * DD + d];
    __shared__ float part[4][DD];
    part[sg][d] = s;
    __syncthreads();
    if (sg == 0)
        csum[((size_t)bh * 16 + c) * DD + d] = part[0][d] + part[1][d] + part[2][d] + part[3][d];
}

// ---------------------------------------------------------------------------
// cumsum: V prefix sums -> out. 512 blocks.
__global__ __launch_bounds__(256) void cumsum_kernel(
        const float* __restrict__ V, const float* __restrict__ csum,
        float* __restrict__ out) {
    int tid = threadIdx.x;
    int x = blockIdx.x;
    int bhLo = x & 7, r = x >> 3;
    int bhHi = r & 3, c = r >> 2;
    int bh = bhHi * 8 + bhLo;
    int d = tid & 63, sg = tid >> 6;
    size_t base = (size_t)bh * LL * DD;
    int row0 = c * 128 + sg * 32;
    float v[32];
    #pragma unroll
    for (int j = 0; j < 32; ++j) v[j] = V[base + (size_t)(row0 + j) * DD + d];
    float s = 0.f;
    #pragma unroll
    for (int j = 0; j < 32; ++j) s += v[j];
    __shared__ float part[4][DD];
    part[sg][d] = s;
    __syncthreads();
    float pre = 0.f;
    for (int cc = 0; cc < c; ++cc) pre += csum[((size_t)bh * 16 + cc) * DD + d];
    for (int ss = 0; ss < sg; ++ss) pre += part[ss][d];
    float acc = pre;
    #pragma unroll
    for (int j = 0; j < 32; ++j) {
        acc += v[j];
        out[base + (size_t)(row0 + j) * DD + d] = acc;
    }
}

// ---------------------------------------------------------------------------
// radix top-40 of M (8 bits/pass, 4 passes); parallel suffix scan for the
// bucket selection (was a 255-iteration serial loop per thread). 32 blocks.
__global__ __launch_bounds__(256) void radix_kernel(
        const float* __restrict__ M, int* __restrict__ topk) {
    int tid = threadIdx.x;
    int bh = blockIdx.x;
    __shared__ unsigned hist[256];
    __shared__ unsigned sfx[256];
    __shared__ unsigned bc_prefix, bc_need;
    __shared__ unsigned cnt_gt, cnt_eq;
    __shared__ int eqlist[128];

    unsigned v[8];
    #pragma unroll
    for (int j = 0; j < 8; ++j)
        v[j] = ordu(M[(size_t)bh * LL + tid + j * 256]);

    unsigned prefix = 0, need = SK;
    #pragma unroll
    for (int pass = 0; pass < 4; ++pass) {
        const int s = 24 - 8 * pass;
        const unsigned maskHigh = (pass == 0) ? 0u : (0xFFFFFFFFu << (s + 8));
        hist[tid] = 0;
        __syncthreads();
        #pragma unroll
        for (int j = 0; j < 8; ++j)
            if (((v[j] ^ prefix) & maskHigh) == 0)
                atomicAdd(&hist[(v[j] >> s) & 0xFF], 1u);
        __syncthreads();
        // inclusive suffix scan of hist into sfx (log-tree, 8 steps)
        sfx[tid] = hist[tid];
        __syncthreads();
        #pragma unroll
        for (int off = 1; off < 256; off <<= 1) {
            unsigned t = (tid + off < 256) ? sfx[tid + off] : 0u;
            __syncthreads();
            sfx[tid] += t;
            __syncthreads();
        }
        unsigned above = (tid < 255) ? sfx[tid + 1] : 0u;
        if (above < need && sfx[tid] >= need) {
            bc_prefix = prefix | ((unsigned)tid << s);
            bc_need = need - above;
        }
        __syncthreads();
        prefix = bc_prefix;
        need = bc_need;
        __syncthreads();
    }
    unsigned T = prefix;
    if (tid == 0) { cnt_gt = 0; cnt_eq = 0; }
    __syncthreads();
    #pragma unroll
    for (int j = 0; j < 8; ++j) {
        int idx = tid + j * 256;
        if (v[j] > T) { unsigned p = atomicAdd(&cnt_gt, 1u); topk[bh * SK + p] = idx; }
        else if (v[j] == T) { unsigned p = atomicAdd(&cnt_eq, 1u); if (p < 128) eqlist[p] = idx; }
    }
    __syncthreads();
    if (tid == 0) {
        int ne = (int)min(cnt_eq, 128u);
        unsigned base = cnt_gt;       // == SK - need
        for (unsigned r2 = 0; r2 < need; ++r2) {
            int bj = 0, bv = 0x7FFFFFFF;
            for (int j = 0; j < ne; ++j)
                if (eqlist[j] < bv) { bv = eqlist[j]; bj = j; }
            topk[bh * SK + base + r2] = bv;
            eqlist[bj] = 0x7FFFFFFF;
        }
    }
}

// ---------------------------------------------------------------------------
// attn: one block per (bh, key-chunk of CK). Stages all 40 Q rows in LDS,
// computes scores for all 40 u's vs the chunk, writes per-(u,chunk) partials.
__global__ __launch_bounds__(256) void attn_kernel(
        const float* __restrict__ Q, const float* __restrict__ K,
        const float* __restrict__ V, const int* __restrict__ topk,
        float* __restrict__ pm, float* __restrict__ pl,
        float* __restrict__ po) {
    int x = blockIdx.x;               // [0, 512)
    int bhLo = x & 7;                 // XCD affinity
    int r = x >> 3;                   // [0,64)
    int c = r & 15;                   // chunk [0,NC)
    int bhHi = r >> 4;                // [0,4)
    int bh = bhHi * 8 + bhLo;
    int tid = threadIdx.x;
    int w = tid >> 6, lane = tid & 63;
    int cbase = c * CK;

    __shared__ int qp[SK];
    __shared__ float4 sq4[SK][16];     // 10 KB: 40 Q rows
    __shared__ float SC[CK][SK + 1];   // 21 KB, pad 41 -> conflict-free

    if (tid < SK) qp[tid] = topk[bh * SK + tid];
    __syncthreads();
    const float4* Q4 = (const float4*)Q;
    const float4* K4 = (const float4*)K;
    const float4* V4 = (const float4*)V;
    for (int i = tid; i < SK * 16; i += 256) {
        int u = i >> 4, j = i & 15;
        sq4[u][j] = Q4[((size_t)bh * LL + qp[u]) * 16 + j];
    }
    __syncthreads();

    // ---- Phase A: scores. thread = (key kk, half of D); K half-row in regs.
    {
        int half = tid & 1;
        int kk = tid >> 1;            // [0,128)
        int kg = cbase + kk;          // global key index
        size_t kb4 = (size_t)bh * LL * 16;
        float4 kreg[8];
        const float4* kr = K4 + kb4 + (size_t)kg * 16 + half * 8;
        #pragma unroll
        for (int j = 0; j < 8; ++j) kreg[j] = kr[j];
        #pragma unroll 4
        for (int u = 0; u < SK; ++u) {
            int qpu = qp[u];
            if (cbase > qpu) {        // chunk fully masked for this u (uniform)
                if (half == 0) SC[kk][u] = -INFINITY;
                continue;
            }
            float pa = 0.f, pb = 0.f;
            #pragma unroll
            for (int j = 0; j < 4; ++j) {
                float4 qv = sq4[u][half * 8 + j];
                pa += kreg[j].x * qv.x + kreg[j].y * qv.y + kreg[j].z * qv.z + kreg[j].w * qv.w;
            }
            #pragma unroll
            for (int j = 4; j < 8; ++j) {
                float4 qv = sq4[u][half * 8 + j];
                pb += kreg[j].x * qv.x + kreg[j].y * qv.y + kreg[j].z * qv.z + kreg[j].w * qv.w;
            }
            float p = pa + pb;
            p += __shfl_xor(p, 1, 64);   // combine the two halves
            if (half == 0) SC[kk][u] = (kg <= qpu) ? p * 0.125f : -INFINITY;
        }
    }
    __syncthreads();

    // ---- Phase B: per-u chunk max + exp + sumexp (wave w handles u = w,w+4,...)
    for (int u = w; u < SK; u += 4) {
        float s0 = SC[lane][u], s1 = SC[lane + 64][u];
        float m = fmaxf(s0, s1);
        #pragma unroll
        for (int off = 32; off > 0; off >>= 1) m = fmaxf(m, __shfl_xor(m, off, 64));
        float e0 = 0.f, e1 = 0.f;
        if (m != -INFINITY) {
            e0 = expf(s0 - m);           // s==-inf -> 0
            e1 = expf(s1 - m);
        }
        SC[lane][u] = e0;
        SC[lane + 64][u] = e1;
        float ls = e0 + e1;
        #pragma unroll
        for (int off = 32; off > 0; off >>= 1) ls += __shfl_xor(ls, off, 64);
        if (lane == 0) {
            size_t pb = (size_t)(bh * SK + u) * NC + c;
            pm[pb] = m;
            pl[pb] = ls;
        }
    }
    __syncthreads();

    // ---- Phase C: PV = P(40xCK) x V(CKx64). thread = (ks, dg, ug):
    {
        int ks = tid & 3;
        int dg = (tid >> 2) & 15;
        int ug = tid >> 6;            // == w
        int u0 = ug * 10;
        float4 acc[10];
        #pragma unroll
        for (int i = 0; i < 10; ++i) acc[i] = make_float4(0.f, 0.f, 0.f, 0.f);
        for (int t = 0; t < CK / 4; ++t) {
            int k = t * 4 + ks;
            float4 vv = V4[((size_t)bh * LL + cbase + k) * 16 + dg];
            #pragma unroll
            for (int i = 0; i < 10; ++i) {
                float pw = SC[k][u0 + i];
                acc[i].x += pw * vv.x; acc[i].y += pw * vv.y;
                acc[i].z += pw * vv.z; acc[i].w += pw * vv.w;
            }
        }
        #pragma unroll
        for (int i = 0; i < 10; ++i) {
            acc[i].x += __shfl_xor(acc[i].x, 1, 64); acc[i].x += __shfl_xor(acc[i].x, 2, 64);
            acc[i].y += __shfl_xor(acc[i].y, 1, 64); acc[i].y += __shfl_xor(acc[i].y, 2, 64);
            acc[i].z += __shfl_xor(acc[i].z, 1, 64); acc[i].z += __shfl_xor(acc[i].z, 2, 64);
            acc[i].w += __shfl_xor(acc[i].w, 1, 64); acc[i].w += __shfl_xor(acc[i].w, 2, 64);
        }
        if (ks == 0) {
            #pragma unroll
            for (int i = 0; i < 10; ++i) {
                float4* dst = (float4*)&po[((size_t)(bh * SK + u0 + i) * NC + c) * DD + dg * 4];
                *dst = acc[i];
            }
        }
    }
}

// ---------------------------------------------------------------------------
// combine: merge NC partials per (bh,u). One wave per group; 4 groups/block.
__global__ __launch_bounds__(256) void combine_kernel(
        const float* __restrict__ pm, const float* __restrict__ pl,
        const float* __restrict__ po, const int* __restrict__ topk,
        float* __restrict__ out) {
    int g = blockIdx.x * 4 + (threadIdx.x >> 6);   // [0, 1280)
    int d = threadIdx.x & 63;
    int qpos = topk[g];
    int bh = g / SK;
    size_t gb = (size_t)g * NC;
    float gm = -INFINITY;
    #pragma unroll
    for (int j = 0; j < NC; ++j) gm = fmaxf(gm, pm[gb + j]);
    float L = 0.f, o = 0.f;
    #pragma unroll
    for (int j = 0; j < NC; ++j) {
        float pmj = pm[gb + j];
        float wj = (pmj == -INFINITY) ? 0.f : expf(pmj - gm);
        L += pl[gb + j] * wj;
        o += po[(gb + j) * DD + d] * wj;
    }
    out[((size_t)bh * LL + qpos) * DD + d] = o / L;
}

// ---------------------------------------------------------------------------
extern "C" void kernel_launch(void* const* d_in, const int* in_sizes, int n_in,
                              void* d_out, int out_size, void* d_ws, size_t ws_size,
                              hipStream_t stream) {
    const float* Q   = (const float*)d_in[0];
    const float* K   = (const float*)d_in[1];
    const float* V   = (const float*)d_in[2];
    const int*   IDX = (const int*)d_in[3];
    float* out = (float*)d_out;

    char* ws = (char*)d_ws;
    float* M    = (float*)ws;  ws += (size_t)BH * LL * sizeof(float);                 // 256 KB
    int*   topk = (int*)ws;    ws += ((size_t)BH * SK * sizeof(int) + 255) & ~255ull;
    float* csum = (float*)ws;  ws += (size_t)BH * 16 * DD * sizeof(float);            // 128 KB
    float* pm   = (float*)ws;  ws += ((size_t)BH * SK * NC * sizeof(float) + 255) & ~255ull;
    float* pl   = (float*)ws;  ws += ((size_t)BH * SK * NC * sizeof(float) + 255) & ~255ull;
    float* po   = (float*)ws;  // BH*SK*NC*DD floats = 5.24 MB

    mkern<<<1024, 256, 0, stream>>>(Q, K, IDX, M);
    vsum_kernel<<<512, 256, 0, stream>>>(V, csum);
    cumsum_kernel<<<512, 256, 0, stream>>>(V, csum, out);
    radix_kernel<<<32, 256, 0, stream>>>(M, topk);
    attn_kernel<<<512, 256, 0, stream>>>(Q, K, V, topk, pm, pl, po);
    combine_kernel<<<320, 256, 0, stream>>>(pm, pl, po, topk, out);
}

// Round 9
// 159.253 us; speedup vs baseline: 1.4685x; 1.0364x over previous
//
#include <hip/hip_runtime.h>
#include <math.h>

#define BB 4
#define HH 8
#define LL 2048
#define DD 64
#define SK 40            // sample_k == u == 40 for L=2048, FACTOR=5
#define BH (BB*HH)       // 32
#define NC 16            // key-chunks per (bh,u) in attn
#define CK 128           // keys per chunk (NC*CK == LL)

__device__ __forceinline__ unsigned ordu(float v) {
    unsigned u = __float_as_uint(v);
    return (u & 0x80000000u) ? ~u : (u | 0x80000000u);
}

__device__ __forceinline__ float dot4(float4 a, float4 b) {
    return a.x * b.x + a.y * b.y + a.z * b.z + a.w * b.w;
}

// ---------------------------------------------------------------------------
// Stage 1: blocks [0,1024) compute M (depth-2 pipelined gather);
//          blocks [1024,1536) V chunk sums (independent, overlaps).
__global__ __launch_bounds__(256) void stage1_kernel(
        const float* __restrict__ Q, const float* __restrict__ K,
        const float* __restrict__ V, const int* __restrict__ IDX,
        float* __restrict__ M, float* __restrict__ csum) {
    int tid = threadIdx.x;
    if (blockIdx.x < 1024) {
        // ----- compute_M: 4 lanes/query, 16 queries/wave, 64 queries/block
        int x = blockIdx.x;
        int bhLo = x & 7;
        int r = x >> 3;                   // [0,128)
        int bhHi = r & 3;
        int chunk = r >> 2;               // [0,32)
        int bh = bhHi * 8 + bhLo;
        int qbase = chunk * 64;
        int w = tid >> 6, lane = tid & 63;
        int qw = lane >> 2, c = lane & 3;
        int qi = w * 16 + qw;
        int qpos = qbase + qi;

        __shared__ int sidx[64 * SK];     // 10 KB
        for (int i = tid; i < 64 * SK; i += 256) sidx[i] = IDX[(size_t)qbase * SK + i];

        const float4* Q4 = (const float4*)Q;
        const float4* K4 = (const float4*)K;
        float4 qreg[4];
        #pragma unroll
        for (int j = 0; j < 4; ++j)
            qreg[j] = Q4[((size_t)bh * LL + qpos) * 16 + j * 4 + c];
        __syncthreads();

        size_t kb4 = (size_t)bh * LL * 16;
        float mx = -INFINITY, sm = 0.f;

        // depth-2 software pipeline: two named load buffers (ka, kb) so two
        // samples' loads are in flight per wave while staying < 64 VGPR.
        float4 ka[4], kb[4];
        {
            const float4* kr = K4 + kb4 + (size_t)sidx[qi * SK] * 16;
            #pragma unroll
            for (int j = 0; j < 4; ++j) ka[j] = kr[j * 4 + c];
        }
        for (int s = 0; s < SK; s += 2) {
            {   // issue loads for sample s+1 (SK even -> always valid)
                const float4* kr = K4 + kb4 + (size_t)sidx[qi * SK + s + 1] * 16;
                #pragma unroll
                for (int j = 0; j < 4; ++j) kb[j] = kr[j * 4 + c];
            }
            {   // consume sample s
                float p = dot4(qreg[0], ka[0]) + dot4(qreg[1], ka[1])
                        + dot4(qreg[2], ka[2]) + dot4(qreg[3], ka[3]);
                p += __shfl_xor(p, 1, 64);
                p += __shfl_xor(p, 2, 64);
                mx = fmaxf(mx, p);
                sm += p;
            }
            if (s + 2 < SK) {   // issue loads for sample s+2
                const float4* kr = K4 + kb4 + (size_t)sidx[qi * SK + s + 2] * 16;
                #pragma unroll
                for (int j = 0; j < 4; ++j) ka[j] = kr[j * 4 + c];
            }
            {   // consume sample s+1
                float p = dot4(qreg[0], kb[0]) + dot4(qreg[1], kb[1])
                        + dot4(qreg[2], kb[2]) + dot4(qreg[3], kb[3]);
                p += __shfl_xor(p, 1, 64);
                p += __shfl_xor(p, 2, 64);
                mx = fmaxf(mx, p);
                sm += p;
            }
        }
        if (c == 0) M[(size_t)bh * LL + qpos] = mx - sm * (1.0f / (float)LL);
    } else {
        // ----- vsum: per-(bh,chunk-of-128) column sums of V
        int x = blockIdx.x - 1024;        // [0,512)
        int bhLo = x & 7, r = x >> 3;
        int bhHi = r & 3, c = r >> 2;     // c in [0,16)
        int bh = bhHi * 8 + bhLo;
        int d = tid & 63, sg = tid >> 6;
        size_t base = (size_t)bh * LL * DD;
        int row0 = c * 128 + sg * 32;
        float s = 0.f;
        for (int j = 0; j < 32; ++j) s += V[base + (size_t)(row0 + j) * DD + d];
        __shared__ float part[4][DD];
        part[sg][d] = s;
        __syncthreads();
        if (sg == 0)
            csum[((size_t)bh * 16 + c) * DD + d] = part[0][d] + part[1][d] + part[2][d] + part[3][d];
    }
}

// ---------------------------------------------------------------------------
// Stage 2: blocks [0,512) cumsum V -> out; blocks [512,544) radix top-40 of M
// (parallel suffix scan).
__global__ __launch_bounds__(256) void stage2_kernel(
        const float* __restrict__ V, const float* __restrict__ csum,
        const float* __restrict__ M, float* __restrict__ out,
        int* __restrict__ topk) {
    int tid = threadIdx.x;
    if (blockIdx.x < 512) {
        // ----- cumsum
        int x = blockIdx.x;
        int bhLo = x & 7, r = x >> 3;
        int bhHi = r & 3, c = r >> 2;
        int bh = bhHi * 8 + bhLo;
        int d = tid & 63, sg = tid >> 6;
        size_t base = (size_t)bh * LL * DD;
        int row0 = c * 128 + sg * 32;
        float v[32];
        #pragma unroll
        for (int j = 0; j < 32; ++j) v[j] = V[base + (size_t)(row0 + j) * DD + d];
        float s = 0.f;
        #pragma unroll
        for (int j = 0; j < 32; ++j) s += v[j];
        __shared__ float part[4][DD];
        part[sg][d] = s;
        __syncthreads();
        float pre = 0.f;
        for (int cc = 0; cc < c; ++cc) pre += csum[((size_t)bh * 16 + cc) * DD + d];
        for (int ss = 0; ss < sg; ++ss) pre += part[ss][d];
        float acc = pre;
        #pragma unroll
        for (int j = 0; j < 32; ++j) {
            acc += v[j];
            out[base + (size_t)(row0 + j) * DD + d] = acc;
        }
    } else {
        // ----- radix top-40 (8 bits/pass, 4 passes); unordered emission.
        int bh = blockIdx.x - 512;
        __shared__ unsigned hist[256];
        __shared__ unsigned sfx[256];
        __shared__ unsigned bc_prefix, bc_need;
        __shared__ unsigned cnt_gt, cnt_eq;
        __shared__ int eqlist[128];

        unsigned v[8];
        #pragma unroll
        for (int j = 0; j < 8; ++j)
            v[j] = ordu(M[(size_t)bh * LL + tid + j * 256]);

        unsigned prefix = 0, need = SK;
        #pragma unroll
        for (int pass = 0; pass < 4; ++pass) {
            const int s = 24 - 8 * pass;
            const unsigned maskHigh = (pass == 0) ? 0u : (0xFFFFFFFFu << (s + 8));
            hist[tid] = 0;
            __syncthreads();
            #pragma unroll
            for (int j = 0; j < 8; ++j)
                if (((v[j] ^ prefix) & maskHigh) == 0)
                    atomicAdd(&hist[(v[j] >> s) & 0xFF], 1u);
            __syncthreads();
            sfx[tid] = hist[tid];
            __syncthreads();
            #pragma unroll
            for (int off = 1; off < 256; off <<= 1) {
                unsigned t = (tid + off < 256) ? sfx[tid + off] : 0u;
                __syncthreads();
                sfx[tid] += t;
                __syncthreads();
            }
            unsigned above = (tid < 255) ? sfx[tid + 1] : 0u;
            if (above < need && sfx[tid] >= need) {
                bc_prefix = prefix | ((unsigned)tid << s);
                bc_need = need - above;
            }
            __syncthreads();
            prefix = bc_prefix;
            need = bc_need;
            __syncthreads();
        }
        unsigned T = prefix;
        if (tid == 0) { cnt_gt = 0; cnt_eq = 0; }
        __syncthreads();
        #pragma unroll
        for (int j = 0; j < 8; ++j) {
            int idx = tid + j * 256;
            if (v[j] > T) { unsigned p = atomicAdd(&cnt_gt, 1u); topk[bh * SK + p] = idx; }
            else if (v[j] == T) { unsigned p = atomicAdd(&cnt_eq, 1u); if (p < 128) eqlist[p] = idx; }
        }
        __syncthreads();
        if (tid == 0) {
            int ne = (int)min(cnt_eq, 128u);
            unsigned base = cnt_gt;       // == SK - need
            for (unsigned r2 = 0; r2 < need; ++r2) {
                int bj = 0, bv = 0x7FFFFFFF;
                for (int j = 0; j < ne; ++j)
                    if (eqlist[j] < bv) { bv = eqlist[j]; bj = j; }
                topk[bh * SK + base + r2] = bv;
                eqlist[bj] = 0x7FFFFFFF;
            }
        }
    }
}

// ---------------------------------------------------------------------------
// attn: one block per (bh, key-chunk of CK). Stages all 40 Q rows in LDS,
// computes scores for all 40 u's vs the chunk, writes per-(u,chunk) partials.
__global__ __launch_bounds__(256) void attn_kernel(
        const float* __restrict__ Q, const float* __restrict__ K,
        const float* __restrict__ V, const int* __restrict__ topk,
        float* __restrict__ pm, float* __restrict__ pl,
        float* __restrict__ po) {
    int x = blockIdx.x;               // [0, 512)
    int bhLo = x & 7;                 // XCD affinity
    int r = x >> 3;                   // [0,64)
    int c = r & 15;                   // chunk [0,NC)
    int bhHi = r >> 4;                // [0,4)
    int bh = bhHi * 8 + bhLo;
    int tid = threadIdx.x;
    int w = tid >> 6, lane = tid & 63;
    int cbase = c * CK;

    __shared__ int qp[SK];
    __shared__ float4 sq4[SK][16];     // 10 KB: 40 Q rows
    __shared__ float SC[CK][SK + 1];   // 21 KB, pad 41 -> conflict-free

    if (tid < SK) qp[tid] = topk[bh * SK + tid];
    __syncthreads();
    const float4* Q4 = (const float4*)Q;
    const float4* K4 = (const float4*)K;
    const float4* V4 = (const float4*)V;
    for (int i = tid; i < SK * 16; i += 256) {
        int u = i >> 4, j = i & 15;
        sq4[u][j] = Q4[((size_t)bh * LL + qp[u]) * 16 + j];
    }
    __syncthreads();

    // ---- Phase A: scores. thread = (key kk, half of D); K half-row in regs.
    {
        int half = tid & 1;
        int kk = tid >> 1;            // [0,128)
        int kg = cbase + kk;          // global key index
        size_t kb4 = (size_t)bh * LL * 16;
        float4 kreg[8];
        const float4* kr = K4 + kb4 + (size_t)kg * 16 + half * 8;
        #pragma unroll
        for (int j = 0; j < 8; ++j) kreg[j] = kr[j];
        #pragma unroll 4
        for (int u = 0; u < SK; ++u) {
            int qpu = qp[u];
            if (cbase > qpu) {        // chunk fully masked for this u (uniform)
                if (half == 0) SC[kk][u] = -INFINITY;
                continue;
            }
            float pa = 0.f, pb = 0.f;
            #pragma unroll
            for (int j = 0; j < 4; ++j) {
                float4 qv = sq4[u][half * 8 + j];
                pa += kreg[j].x * qv.x + kreg[j].y * qv.y + kreg[j].z * qv.z + kreg[j].w * qv.w;
            }
            #pragma unroll
            for (int j = 4; j < 8; ++j) {
                float4 qv = sq4[u][half * 8 + j];
                pb += kreg[j].x * qv.x + kreg[j].y * qv.y + kreg[j].z * qv.z + kreg[j].w * qv.w;
            }
            float p = pa + pb;
            p += __shfl_xor(p, 1, 64);   // combine the two halves
            if (half == 0) SC[kk][u] = (kg <= qpu) ? p * 0.125f : -INFINITY;
        }
    }
    __syncthreads();

    // ---- Phase B: per-u chunk max + exp + sumexp (wave w handles u = w,w+4,...)
    for (int u = w; u < SK; u += 4) {
        float s0 = SC[lane][u], s1 = SC[lane + 64][u];
        float m = fmaxf(s0, s1);
        #pragma unroll
        for (int off = 32; off > 0; off >>= 1) m = fmaxf(m, __shfl_xor(m, off, 64));
        float e0 = 0.f, e1 = 0.f;
        if (m != -INFINITY) {
            e0 = expf(s0 - m);           // s==-inf -> 0
            e1 = expf(s1 - m);
        }
        SC[lane][u] = e0;
        SC[lane + 64][u] = e1;
        float ls = e0 + e1;
        #pragma unroll
        for (int off = 32; off > 0; off >>= 1) ls += __shfl_xor(ls, off, 64);
        if (lane == 0) {
            size_t pb = (size_t)(bh * SK + u) * NC + c;
            pm[pb] = m;
            pl[pb] = ls;
        }
    }
    __syncthreads();

    // ---- Phase C: PV = P(40xCK) x V(CKx64). thread = (ks, dg, ug):
    {
        int ks = tid & 3;
        int dg = (tid >> 2) & 15;
        int ug = tid >> 6;            // == w
        int u0 = ug * 10;
        float4 acc[10];
        #pragma unroll
        for (int i = 0; i < 10; ++i) acc[i] = make_float4(0.f, 0.f, 0.f, 0.f);
        for (int t = 0; t < CK / 4; ++t) {
            int k = t * 4 + ks;
            float4 vv = V4[((size_t)bh * LL + cbase + k) * 16 + dg];
            #pragma unroll
            for (int i = 0; i < 10; ++i) {
                float pw = SC[k][u0 + i];
                acc[i].x += pw * vv.x; acc[i].y += pw * vv.y;
                acc[i].z += pw * vv.z; acc[i].w += pw * vv.w;
            }
        }
        #pragma unroll
        for (int i = 0; i < 10; ++i) {
            acc[i].x += __shfl_xor(acc[i].x, 1, 64); acc[i].x += __shfl_xor(acc[i].x, 2, 64);
            acc[i].y += __shfl_xor(acc[i].y, 1, 64); acc[i].y += __shfl_xor(acc[i].y, 2, 64);
            acc[i].z += __shfl_xor(acc[i].z, 1, 64); acc[i].z += __shfl_xor(acc[i].z, 2, 64);
            acc[i].w += __shfl_xor(acc[i].w, 1, 64); acc[i].w += __shfl_xor(acc[i].w, 2, 64);
        }
        if (ks == 0) {
            #pragma unroll
            for (int i = 0; i < 10; ++i) {
                float4* dst = (float4*)&po[((size_t)(bh * SK + u0 + i) * NC + c) * DD + dg * 4];
                *dst = acc[i];
            }
        }
    }
}

// ---------------------------------------------------------------------------
// combine: merge NC partials per (bh,u). One wave per group; 4 groups/block.
__global__ __launch_bounds__(256) void combine_kernel(
        const float* __restrict__ pm, const float* __restrict__ pl,
        const float* __restrict__ po, const int* __restrict__ topk,
        float* __restrict__ out) {
    int g = blockIdx.x * 4 + (threadIdx.x >> 6);   // [0, 1280)
    int d = threadIdx.x & 63;
    int qpos = topk[g];
    int bh = g / SK;
    size_t gb = (size_t)g * NC;
    float gm = -INFINITY;
    #pragma unroll
    for (int j = 0; j < NC; ++j) gm = fmaxf(gm, pm[gb + j]);
    float L = 0.f, o = 0.f;
    #pragma unroll
    for (int j = 0; j < NC; ++j) {
        float pmj = pm[gb + j];
        float wj = (pmj == -INFINITY) ? 0.f : expf(pmj - gm);
        L += pl[gb + j] * wj;
        o += po[(gb + j) * DD + d] * wj;
    }
    out[((size_t)bh * LL + qpos) * DD + d] = o / L;
}

// ---------------------------------------------------------------------------
extern "C" void kernel_launch(void* const* d_in, const int* in_sizes, int n_in,
                              void* d_out, int out_size, void* d_ws, size_t ws_size,
                              hipStream_t stream) {
    const float* Q   = (const float*)d_in[0];
    const float* K   = (const float*)d_in[1];
    const float* V   = (const float*)d_in[2];
    const int*   IDX = (const int*)d_in[3];
    float* out = (float*)d_out;

    char* ws = (char*)d_ws;
    float* M    = (float*)ws;  ws += (size_t)BH * LL * sizeof(float);                 // 256 KB
    int*   topk = (int*)ws;    ws += ((size_t)BH * SK * sizeof(int) + 255) & ~255ull;
    float* csum = (float*)ws;  ws += (size_t)BH * 16 * DD * sizeof(float);            // 128 KB
    float* pm   = (float*)ws;  ws += ((size_t)BH * SK * NC * sizeof(float) + 255) & ~255ull;
    float* pl   = (float*)ws;  ws += ((size_t)BH * SK * NC * sizeof(float) + 255) & ~255ull;
    float* po   = (float*)ws;  // BH*SK*NC*DD floats = 5.24 MB

    stage1_kernel<<<1536, 256, 0, stream>>>(Q, K, V, IDX, M, csum);
    stage2_kernel<<<544, 256, 0, stream>>>(V, csum, M, out, topk);
    attn_kernel<<<512, 256, 0, stream>>>(Q, K, V, topk, pm, pl, po);
    combine_kernel<<<320, 256, 0, stream>>>(pm, pl, po, topk, out);
}

// Round 10
// 157.882 us; speedup vs baseline: 1.4813x; 1.0087x over previous
//
#include <hip/hip_runtime.h>
#include <math.h>

#define BB 4
#define HH 8
#define LL 2048
#define DD 64
#define SK 40            // sample_k == u == 40 for L=2048, FACTOR=5
#define BH (BB*HH)       // 32
#define NC 16            // key-chunks per (bh,u) in attn
#define CK 128           // keys per chunk (NC*CK == LL)

__device__ __forceinline__ unsigned ordu(float v) {
    unsigned u = __float_as_uint(v);
    return (u & 0x80000000u) ? ~u : (u | 0x80000000u);
}

__device__ __forceinline__ float dot4(float4 a, float4 b) {
    return a.x * b.x + a.y * b.y + a.z * b.z + a.w * b.w;
}

// ---------------------------------------------------------------------------
// Stage 1: blocks [0,1024) compute M (depth-2 pipelined gather);
//          blocks [1024,1536) V chunk sums (independent, overlaps).
__global__ __launch_bounds__(256) void stage1_kernel(
        const float* __restrict__ Q, const float* __restrict__ K,
        const float* __restrict__ V, const int* __restrict__ IDX,
        float* __restrict__ M, float* __restrict__ csum) {
    int tid = threadIdx.x;
    if (blockIdx.x < 1024) {
        // ----- compute_M: 4 lanes/query, 16 queries/wave, 64 queries/block
        int x = blockIdx.x;
        int bhLo = x & 7;
        int r = x >> 3;                   // [0,128)
        int bhHi = r & 3;
        int chunk = r >> 2;               // [0,32)
        int bh = bhHi * 8 + bhLo;
        int qbase = chunk * 64;
        int w = tid >> 6, lane = tid & 63;
        int qw = lane >> 2, c = lane & 3;
        int qi = w * 16 + qw;
        int qpos = qbase + qi;

        __shared__ int sidx[64 * SK];     // 10 KB
        for (int i = tid; i < 64 * SK; i += 256) sidx[i] = IDX[(size_t)qbase * SK + i];

        const float4* Q4 = (const float4*)Q;
        const float4* K4 = (const float4*)K;
        float4 qreg[4];
        #pragma unroll
        for (int j = 0; j < 4; ++j)
            qreg[j] = Q4[((size_t)bh * LL + qpos) * 16 + j * 4 + c];
        __syncthreads();

        size_t kb4 = (size_t)bh * LL * 16;
        float mx = -INFINITY, sm = 0.f;

        // depth-2 software pipeline: two named load buffers (ka, kb).
        float4 ka[4], kb[4];
        {
            const float4* kr = K4 + kb4 + (size_t)sidx[qi * SK] * 16;
            #pragma unroll
            for (int j = 0; j < 4; ++j) ka[j] = kr[j * 4 + c];
        }
        for (int s = 0; s < SK; s += 2) {
            {   // issue loads for sample s+1 (SK even -> always valid)
                const float4* kr = K4 + kb4 + (size_t)sidx[qi * SK + s + 1] * 16;
                #pragma unroll
                for (int j = 0; j < 4; ++j) kb[j] = kr[j * 4 + c];
            }
            {   // consume sample s
                float p = dot4(qreg[0], ka[0]) + dot4(qreg[1], ka[1])
                        + dot4(qreg[2], ka[2]) + dot4(qreg[3], ka[3]);
                p += __shfl_xor(p, 1, 64);
                p += __shfl_xor(p, 2, 64);
                mx = fmaxf(mx, p);
                sm += p;
            }
            if (s + 2 < SK) {   // issue loads for sample s+2
                const float4* kr = K4 + kb4 + (size_t)sidx[qi * SK + s + 2] * 16;
                #pragma unroll
                for (int j = 0; j < 4; ++j) ka[j] = kr[j * 4 + c];
            }
            {   // consume sample s+1
                float p = dot4(qreg[0], kb[0]) + dot4(qreg[1], kb[1])
                        + dot4(qreg[2], kb[2]) + dot4(qreg[3], kb[3]);
                p += __shfl_xor(p, 1, 64);
                p += __shfl_xor(p, 2, 64);
                mx = fmaxf(mx, p);
                sm += p;
            }
        }
        if (c == 0) M[(size_t)bh * LL + qpos] = mx - sm * (1.0f / (float)LL);
    } else {
        // ----- vsum: per-(bh,chunk-of-128) column sums of V
        int x = blockIdx.x - 1024;        // [0,512)
        int bhLo = x & 7, r = x >> 3;
        int bhHi = r & 3, c = r >> 2;     // c in [0,16)
        int bh = bhHi * 8 + bhLo;
        int d = tid & 63, sg = tid >> 6;
        size_t base = (size_t)bh * LL * DD;
        int row0 = c * 128 + sg * 32;
        float s = 0.f;
        for (int j = 0; j < 32; ++j) s += V[base + (size_t)(row0 + j) * DD + d];
        __shared__ float part[4][DD];
        part[sg][d] = s;
        __syncthreads();
        if (sg == 0)
            csum[((size_t)bh * 16 + c) * DD + d] = part[0][d] + part[1][d] + part[2][d] + part[3][d];
    }
}

// ---------------------------------------------------------------------------
// radix top-40 of M (8 bits/pass, 4 passes); parallel suffix scan. 32 blocks.
__global__ __launch_bounds__(256) void radix_kernel(
        const float* __restrict__ M, int* __restrict__ topk) {
    int tid = threadIdx.x;
    int bh = blockIdx.x;
    __shared__ unsigned hist[256];
    __shared__ unsigned sfx[256];
    __shared__ unsigned bc_prefix, bc_need;
    __shared__ unsigned cnt_gt, cnt_eq;
    __shared__ int eqlist[128];

    unsigned v[8];
    #pragma unroll
    for (int j = 0; j < 8; ++j)
        v[j] = ordu(M[(size_t)bh * LL + tid + j * 256]);

    unsigned prefix = 0, need = SK;
    #pragma unroll
    for (int pass = 0; pass < 4; ++pass) {
        const int s = 24 - 8 * pass;
        const unsigned maskHigh = (pass == 0) ? 0u : (0xFFFFFFFFu << (s + 8));
        hist[tid] = 0;
        __syncthreads();
        #pragma unroll
        for (int j = 0; j < 8; ++j)
            if (((v[j] ^ prefix) & maskHigh) == 0)
                atomicAdd(&hist[(v[j] >> s) & 0xFF], 1u);
        __syncthreads();
        sfx[tid] = hist[tid];
        __syncthreads();
        #pragma unroll
        for (int off = 1; off < 256; off <<= 1) {
            unsigned t = (tid + off < 256) ? sfx[tid + off] : 0u;
            __syncthreads();
            sfx[tid] += t;
            __syncthreads();
        }
        unsigned above = (tid < 255) ? sfx[tid + 1] : 0u;
        if (above < need && sfx[tid] >= need) {
            bc_prefix = prefix | ((unsigned)tid << s);
            bc_need = need - above;
        }
        __syncthreads();
        prefix = bc_prefix;
        need = bc_need;
        __syncthreads();
    }
    unsigned T = prefix;
    if (tid == 0) { cnt_gt = 0; cnt_eq = 0; }
    __syncthreads();
    #pragma unroll
    for (int j = 0; j < 8; ++j) {
        int idx = tid + j * 256;
        if (v[j] > T) { unsigned p = atomicAdd(&cnt_gt, 1u); topk[bh * SK + p] = idx; }
        else if (v[j] == T) { unsigned p = atomicAdd(&cnt_eq, 1u); if (p < 128) eqlist[p] = idx; }
    }
    __syncthreads();
    if (tid == 0) {
        int ne = (int)min(cnt_eq, 128u);
        unsigned base = cnt_gt;       // == SK - need
        for (unsigned r2 = 0; r2 < need; ++r2) {
            int bj = 0, bv = 0x7FFFFFFF;
            for (int j = 0; j < ne; ++j)
                if (eqlist[j] < bv) { bv = eqlist[j]; bj = j; }
            topk[bh * SK + base + r2] = bv;
            eqlist[bj] = 0x7FFFFFFF;
        }
    }
}

// ---------------------------------------------------------------------------
// Fused attn + cumsum: independent work co-scheduled so BW-bound cumsum
// overlaps compute-bound attn. Blocks [0,512): attn chunks (dispatched first,
// critical path for combine); blocks [512,1024): V cumsum -> out.
__global__ __launch_bounds__(256) void attn_cumsum_kernel(
        const float* __restrict__ Q, const float* __restrict__ K,
        const float* __restrict__ V, const int* __restrict__ topk,
        const float* __restrict__ csum, float* __restrict__ out,
        float* __restrict__ pm, float* __restrict__ pl,
        float* __restrict__ po) {
    int tid = threadIdx.x;
    __shared__ int qp[SK];
    __shared__ float4 sq4[SK][16];     // 10 KB
    __shared__ float SC[CK][SK + 1];   // 21 KB
    __shared__ float part[4][DD];      // 1 KB (cumsum)

    if (blockIdx.x < 512) {
        // ================= attn chunk =================
        int x = blockIdx.x;
        int bhLo = x & 7;                 // XCD affinity
        int r = x >> 3;                   // [0,64)
        int c = r & 15;                   // chunk [0,NC)
        int bhHi = r >> 4;                // [0,4)
        int bh = bhHi * 8 + bhLo;
        int w = tid >> 6, lane = tid & 63;
        int cbase = c * CK;

        if (tid < SK) qp[tid] = topk[bh * SK + tid];
        __syncthreads();
        const float4* Q4 = (const float4*)Q;
        const float4* K4 = (const float4*)K;
        const float4* V4 = (const float4*)V;
        for (int i = tid; i < SK * 16; i += 256) {
            int u = i >> 4, j = i & 15;
            sq4[u][j] = Q4[((size_t)bh * LL + qp[u]) * 16 + j];
        }
        __syncthreads();

        // ---- Phase A: scores. thread = (key kk, half of D).
        {
            int half = tid & 1;
            int kk = tid >> 1;            // [0,128)
            int kg = cbase + kk;
            size_t kb4 = (size_t)bh * LL * 16;
            float4 kreg[8];
            const float4* kr = K4 + kb4 + (size_t)kg * 16 + half * 8;
            #pragma unroll
            for (int j = 0; j < 8; ++j) kreg[j] = kr[j];
            #pragma unroll 4
            for (int u = 0; u < SK; ++u) {
                int qpu = qp[u];
                if (cbase > qpu) {
                    if (half == 0) SC[kk][u] = -INFINITY;
                    continue;
                }
                float pa = 0.f, pb = 0.f;
                #pragma unroll
                for (int j = 0; j < 4; ++j) {
                    float4 qv = sq4[u][half * 8 + j];
                    pa += kreg[j].x * qv.x + kreg[j].y * qv.y + kreg[j].z * qv.z + kreg[j].w * qv.w;
                }
                #pragma unroll
                for (int j = 4; j < 8; ++j) {
                    float4 qv = sq4[u][half * 8 + j];
                    pb += kreg[j].x * qv.x + kreg[j].y * qv.y + kreg[j].z * qv.z + kreg[j].w * qv.w;
                }
                float p = pa + pb;
                p += __shfl_xor(p, 1, 64);
                if (half == 0) SC[kk][u] = (kg <= qpu) ? p * 0.125f : -INFINITY;
            }
        }
        __syncthreads();

        // ---- Phase B: per-u chunk max + exp + sumexp
        for (int u = w; u < SK; u += 4) {
            float s0 = SC[lane][u], s1 = SC[lane + 64][u];
            float m = fmaxf(s0, s1);
            #pragma unroll
            for (int off = 32; off > 0; off >>= 1) m = fmaxf(m, __shfl_xor(m, off, 64));
            float e0 = 0.f, e1 = 0.f;
            if (m != -INFINITY) {
                e0 = expf(s0 - m);
                e1 = expf(s1 - m);
            }
            SC[lane][u] = e0;
            SC[lane + 64][u] = e1;
            float ls = e0 + e1;
            #pragma unroll
            for (int off = 32; off > 0; off >>= 1) ls += __shfl_xor(ls, off, 64);
            if (lane == 0) {
                size_t pb = (size_t)(bh * SK + u) * NC + c;
                pm[pb] = m;
                pl[pb] = ls;
            }
        }
        __syncthreads();

        // ---- Phase C: PV
        {
            int ks = tid & 3;
            int dg = (tid >> 2) & 15;
            int ug = tid >> 6;
            int u0 = ug * 10;
            float4 acc[10];
            #pragma unroll
            for (int i = 0; i < 10; ++i) acc[i] = make_float4(0.f, 0.f, 0.f, 0.f);
            for (int t = 0; t < CK / 4; ++t) {
                int k = t * 4 + ks;
                float4 vv = V4[((size_t)bh * LL + cbase + k) * 16 + dg];
                #pragma unroll
                for (int i = 0; i < 10; ++i) {
                    float pw = SC[k][u0 + i];
                    acc[i].x += pw * vv.x; acc[i].y += pw * vv.y;
                    acc[i].z += pw * vv.z; acc[i].w += pw * vv.w;
                }
            }
            #pragma unroll
            for (int i = 0; i < 10; ++i) {
                acc[i].x += __shfl_xor(acc[i].x, 1, 64); acc[i].x += __shfl_xor(acc[i].x, 2, 64);
                acc[i].y += __shfl_xor(acc[i].y, 1, 64); acc[i].y += __shfl_xor(acc[i].y, 2, 64);
                acc[i].z += __shfl_xor(acc[i].z, 1, 64); acc[i].z += __shfl_xor(acc[i].z, 2, 64);
                acc[i].w += __shfl_xor(acc[i].w, 1, 64); acc[i].w += __shfl_xor(acc[i].w, 2, 64);
            }
            if (ks == 0) {
                #pragma unroll
                for (int i = 0; i < 10; ++i) {
                    float4* dst = (float4*)&po[((size_t)(bh * SK + u0 + i) * NC + c) * DD + dg * 4];
                    *dst = acc[i];
                }
            }
        }
    } else {
        // ================= cumsum chunk =================
        int x = blockIdx.x - 512;
        int bhLo = x & 7, r = x >> 3;
        int bhHi = r & 3, c = r >> 2;
        int bh = bhHi * 8 + bhLo;
        int d = tid & 63, sg = tid >> 6;
        size_t base = (size_t)bh * LL * DD;
        int row0 = c * 128 + sg * 32;
        float v[32];
        #pragma unroll
        for (int j = 0; j < 32; ++j) v[j] = V[base + (size_t)(row0 + j) * DD + d];
        float s = 0.f;
        #pragma unroll
        for (int j = 0; j < 32; ++j) s += v[j];
        part[sg][d] = s;
        __syncthreads();
        float pre = 0.f;
        for (int cc = 0; cc < c; ++cc) pre += csum[((size_t)bh * 16 + cc) * DD + d];
        for (int ss = 0; ss < sg; ++ss) pre += part[ss][d];
        float acc = pre;
        #pragma unroll
        for (int j = 0; j < 32; ++j) {
            acc += v[j];
            out[base + (size_t)(row0 + j) * DD + d] = acc;
        }
    }
}

// ---------------------------------------------------------------------------
// combine: merge NC partials per (bh,u). One wave per group; 4 groups/block.
__global__ __launch_bounds__(256) void combine_kernel(
        const float* __restrict__ pm, const float* __restrict__ pl,
        const float* __restrict__ po, const int* __restrict__ topk,
        float* __restrict__ out) {
    int g = blockIdx.x * 4 + (threadIdx.x >> 6);   // [0, 1280)
    int d = threadIdx.x & 63;
    int qpos = topk[g];
    int bh = g / SK;
    size_t gb = (size_t)g * NC;
    float gm = -INFINITY;
    #pragma unroll
    for (int j = 0; j < NC; ++j) gm = fmaxf(gm, pm[gb + j]);
    float L = 0.f, o = 0.f;
    #pragma unroll
    for (int j = 0; j < NC; ++j) {
        float pmj = pm[gb + j];
        float wj = (pmj == -INFINITY) ? 0.f : expf(pmj - gm);
        L += pl[gb + j] * wj;
        o += po[(gb + j) * DD + d] * wj;
    }
    out[((size_t)bh * LL + qpos) * DD + d] = o / L;
}

// ---------------------------------------------------------------------------
extern "C" void kernel_launch(void* const* d_in, const int* in_sizes, int n_in,
                              void* d_out, int out_size, void* d_ws, size_t ws_size,
                              hipStream_t stream) {
    const float* Q   = (const float*)d_in[0];
    const float* K   = (const float*)d_in[1];
    const float* V   = (const float*)d_in[2];
    const int*   IDX = (const int*)d_in[3];
    float* out = (float*)d_out;

    char* ws = (char*)d_ws;
    float* M    = (float*)ws;  ws += (size_t)BH * LL * sizeof(float);                 // 256 KB
    int*   topk = (int*)ws;    ws += ((size_t)BH * SK * sizeof(int) + 255) & ~255ull;
    float* csum = (float*)ws;  ws += (size_t)BH * 16 * DD * sizeof(float);            // 128 KB
    float* pm   = (float*)ws;  ws += ((size_t)BH * SK * NC * sizeof(float) + 255) & ~255ull;
    float* pl   = (float*)ws;  ws += ((size_t)BH * SK * NC * sizeof(float) + 255) & ~255ull;
    float* po   = (float*)ws;  // BH*SK*NC*DD floats = 5.24 MB

    stage1_kernel<<<1536, 256, 0, stream>>>(Q, K, V, IDX, M, csum);
    radix_kernel<<<32, 256, 0, stream>>>(M, topk);
    attn_cumsum_kernel<<<1024, 256, 0, stream>>>(Q, K, V, topk, csum, out, pm, pl, po);
    combine_kernel<<<320, 256, 0, stream>>>(pm, pl, po, topk, out);
}